// Round 1
// 419.876 us; speedup vs baseline: 1.0138x; 1.0138x over previous
//
#include <hip/hip_runtime.h>

// DCT upsample: out[img] = M * x[img] * M^T,  M = E*D (960x768), closed-form
// Dirichlet kernel:
//   M[i][n] = (1 + S(p1) + S(p2))/960,  S = sin(767u)cos(768u)/sin(u), u=pi*p/15360
// Restructured so M is the A operand of BOTH gemms:
//   T' = M * x^T      (Bt = x row-major, bf16-converted)   [960 x 768]
//   out = M * T'^T    (Bt = T')                            [960 x 960]
// GEMM: C = A * Bt^T, bf16, fp32 accum, mfma 16x16x32, glds width-16 staging.
// V2: 2-phase double-buffered K-loop (T3 "minimum 2-phase"):
//   STAGE(next tile) issued BEFORE compute(current) so the vmcnt(0) drain at
//   the single barrier per tile is covered by 32 MFMAs of work. BK=64,
//   LDS = 2 bufs x (128x64 A + 128x64 B) = 64 KiB.
//   XOR chunk swizzle: phys 16B-chunk p of row r holds logical chunk
//   p ^ ((r>>1)&7); applied on the (per-lane) global source address since
//   global_load_lds destinations must stay linear; fragment reads apply the
//   same XOR -> conflict-free ds_read_b128.

#define HW 768
#define OHW 960
#define NIMG 48

typedef __attribute__((ext_vector_type(8))) short short8;
typedef __attribute__((ext_vector_type(4))) float f32x4;
typedef __attribute__((ext_vector_type(4))) float float4v;
typedef __attribute__((ext_vector_type(4))) unsigned short us4;

__device__ __forceinline__ unsigned short f2bf(float f) {
    union { float f; unsigned int u; } v; v.f = f;
    unsigned int u = v.u;
    return (unsigned short)((u + 0x7FFFu + ((u >> 16) & 1u)) >> 16);
}

__device__ __forceinline__ void glds16(const void* g, void* l) {
    __builtin_amdgcn_global_load_lds(
        (const __attribute__((address_space(1))) void*)g,
        (__attribute__((address_space(3))) void*)l, 16, 0, 0);
}

// ---------------- closed-form M fill ----------------
__device__ __forceinline__ float dsum(int p) {
    int n1 = (767 * p) % 30720;
    int n2 = (768 * p) % 30720;
    const float w = (float)(3.14159265358979323846 / 15360.0);
    return sinf((float)n1 * w) * cosf((float)n2 * w) / sinf((float)p * w);
}

__global__ void fill_M(unsigned short* __restrict__ Mb) {
    int idx = blockIdx.x * 256 + threadIdx.x;
    if (idx >= OHW * HW) return;
    int i = idx / HW, n = idx - i * HW;
    int a = 8 * i + 4, b = 10 * n + 5;
    int p1 = a + b;
    int p2 = a - b; if (p2 < 0) p2 += 15360;
    float m = (1.0f + dsum(p1) + dsum(p2)) * (1.0f / 960.0f);
    Mb[idx] = f2bf(m);
}

// ---------------- streaming f32 -> bf16 convert ----------------
__global__ void conv_bf16(const float* __restrict__ x, unsigned short* __restrict__ xb, int n4) {
    int i = blockIdx.x * 256 + threadIdx.x;
    if (i >= n4) return;
    float4v v = *(const float4v*)(x + (size_t)i * 4);
    us4 o; o.x = f2bf(v.x); o.y = f2bf(v.y); o.z = f2bf(v.z); o.w = f2bf(v.w);
    *(us4*)(xb + (size_t)i * 4) = o;
}

// ---------------- MFMA GEMM (B-transposed, K-major operands) ----------------
// block tile 128x128, BK=64, double-buffered, 4 waves (2x2),
// each wave 64x64 = 4x4 mfma_16x16x32, 2 k-subtiles per LDS tile.
__global__ __launch_bounds__(256) void gemm_bt(
    const unsigned short* __restrict__ A, int lda,
    const unsigned short* __restrict__ Bg, long long strideB, int ldb,
    void* __restrict__ Cg, long long strideC, int ldc,
    int Md, int Nd, int Kd, int out_f32)
{
    __shared__ unsigned short As[2][128 * 64];
    __shared__ unsigned short Bs[2][128 * 64];

    const int tid = threadIdx.x;
    const int wave = tid >> 6, lane = tid & 63;
    const int wm = wave >> 1, wn = wave & 1;
    const int t16 = lane & 15, quad = lane >> 4;
    const int z = blockIdx.z;

    const unsigned short* Bp = Bg + (size_t)z * strideB;
    const int mb = blockIdx.y * 128, nbb = blockIdx.x * 128;

    f32x4 acc[4][4];
#pragma unroll
    for (int i = 0; i < 4; ++i)
#pragma unroll
        for (int j = 0; j < 4; ++j)
            acc[i][j] = (f32x4){0.f, 0.f, 0.f, 0.f};

    // ---- staging geometry (pre-swizzled per-lane global source) ----
    // thread stages 16B chunks c = tid + 256*j (j=0..3) per matrix per tile:
    //   row  r = c>>3 = (tid>>3) + 32*j
    //   phys p = c&7  = tid&7
    //   log  l = p ^ ((r>>1)&7) = (tid&7) ^ ((tid>>4)&7)   (j-independent)
    const int srow = tid >> 3;                            // 0..31
    const int klog = (((tid & 7) ^ ((tid >> 4) & 7))) * 8; // shorts
    const unsigned short* pA[4];
    const unsigned short* pB[4];
#pragma unroll
    for (int j = 0; j < 4; ++j) {
        int ra = mb + srow + 32 * j;  if (ra >= Md) ra = Md - 1;
        int rb = nbb + srow + 32 * j; if (rb >= Nd) rb = Nd - 1;
        pA[j] = A  + (size_t)ra * lda + klog;
        pB[j] = Bp + (size_t)rb * ldb + klog;
    }
    unsigned short* dA = &As[0][0] + tid * 8;  // + j*2048 shorts per chunk
    unsigned short* dB = &Bs[0][0] + tid * 8;

    // ---- fragment read offsets (shorts), per 32-wide k-subtile ks ----
    // logical chunk for (ks, quad) is ks*4+quad; phys = log ^ ((row>>1)&7),
    // and (row>>1)&7 == (t16>>1)&7 for row = wm*64 + mi*16 + t16.
    const int swz = (t16 >> 1) & 7;
    int aOff[2], bOff[2];
#pragma unroll
    for (int ks = 0; ks < 2; ++ks) {
        int ph = ((ks * 4 + quad) ^ swz) * 8;
        aOff[ks] = (wm * 64 + t16) * 64 + ph;
        bOff[ks] = (wn * 64 + t16) * 64 + ph;
    }

#define STAGE(buf, kt) do {                                                   \
    int kk_ = (kt) * 64;                                                      \
    _Pragma("unroll")                                                         \
    for (int j_ = 0; j_ < 4; ++j_)                                            \
        glds16(pA[j_] + kk_, dA + (buf) * 8192 + j_ * 2048);                  \
    _Pragma("unroll")                                                         \
    for (int j_ = 0; j_ < 4; ++j_)                                            \
        glds16(pB[j_] + kk_, dB + (buf) * 8192 + j_ * 2048);                  \
} while (0)

#define COMPUTE(buf) do {                                                     \
    _Pragma("unroll")                                                         \
    for (int ks_ = 0; ks_ < 2; ++ks_) {                                       \
        short8 af_[4], bf_[4];                                                \
        _Pragma("unroll")                                                     \
        for (int mi_ = 0; mi_ < 4; ++mi_)                                     \
            af_[mi_] = *(const short8*)(&As[buf][0] + aOff[ks_] + mi_ * 1024);\
        _Pragma("unroll")                                                     \
        for (int ni_ = 0; ni_ < 4; ++ni_)                                     \
            bf_[ni_] = *(const short8*)(&Bs[buf][0] + bOff[ks_] + ni_ * 1024);\
        _Pragma("unroll")                                                     \
        for (int mi_ = 0; mi_ < 4; ++mi_)                                     \
        _Pragma("unroll")                                                     \
        for (int ni_ = 0; ni_ < 4; ++ni_)                                     \
            acc[mi_][ni_] = __builtin_amdgcn_mfma_f32_16x16x32_bf16(          \
                af_[mi_], bf_[ni_], acc[mi_][ni_], 0, 0, 0);                  \
    }                                                                         \
} while (0)

    const int NT = Kd >> 6;   // K=768 -> 12 tiles (even; loop assumes even NT)

    STAGE(0, 0);
    __syncthreads();

    for (int kt = 0; kt + 2 <= NT; kt += 2) {
        STAGE(1, kt + 1);          // prefetch next tile while computing cur
        COMPUTE(0);
        __syncthreads();           // vmcnt(0)+barrier: buf1 ready, buf0 free
        if (kt + 2 < NT) STAGE(0, kt + 2);
        COMPUTE(1);
        __syncthreads();
    }

#undef STAGE
#undef COMPUTE

    // epilogue: D row = quad*4 + r, col = t16 within each 16x16 tile
    const int gr0 = mb + wm * 64;
    const int gc0 = nbb + wn * 64;
    if (out_f32) {
        float* C = (float*)Cg + (size_t)z * strideC;
#pragma unroll
        for (int mi = 0; mi < 4; ++mi)
#pragma unroll
            for (int ni = 0; ni < 4; ++ni) {
                int col = gc0 + ni * 16 + t16;
                if (col < Nd) {
#pragma unroll
                    for (int r = 0; r < 4; ++r) {
                        int rowg = gr0 + mi * 16 + quad * 4 + r;
                        if (rowg < Md) C[(size_t)rowg * ldc + col] = acc[mi][ni][r];
                    }
                }
            }
    } else {
        unsigned short* C = (unsigned short*)Cg + (size_t)z * strideC;
#pragma unroll
        for (int mi = 0; mi < 4; ++mi)
#pragma unroll
            for (int ni = 0; ni < 4; ++ni) {
                int col = gc0 + ni * 16 + t16;
                if (col < Nd) {
#pragma unroll
                    for (int r = 0; r < 4; ++r) {
                        int rowg = gr0 + mi * 16 + quad * 4 + r;
                        if (rowg < Md) C[(size_t)rowg * ldc + col] = f2bf(acc[mi][ni][r]);
                    }
                }
            }
    }
}

extern "C" void kernel_launch(void* const* d_in, const int* in_sizes, int n_in,
                              void* d_out, int out_size, void* d_ws, size_t ws_size,
                              hipStream_t stream) {
    const float* x = (const float*)d_in[0];
    float* out = (float*)d_out;
    char* ws = (char*)d_ws;

    size_t offM  = 0;
    size_t fixed = offM + (size_t)OHW * HW * 2;              // 1,474,560 B
    size_t perImg = (size_t)HW * HW * 2 + (size_t)OHW * HW * 2;

    int nb = 1;
    if (ws_size > fixed + perImg) {
        size_t q = (ws_size - fixed) / perImg;
        nb = (q > 48) ? 48 : (int)q;
        if (nb < 1) nb = 1;
    }

    unsigned short* Mb = (unsigned short*)(ws + offM);
    unsigned short* xb = (unsigned short*)(ws + fixed);
    unsigned short* T  = (unsigned short*)(ws + fixed + (size_t)nb * HW * HW * 2);

    fill_M<<<(OHW * HW + 255) / 256, 256, 0, stream>>>(Mb);

    for (int b0 = 0; b0 < NIMG; b0 += nb) {
        int cur = NIMG - b0; if (cur > nb) cur = nb;
        // xb = bf16(x[b0..b0+cur]), straight streaming convert (no transpose)
        int n4 = cur * (HW * HW / 4);
        conv_bf16<<<(n4 + 255) / 256, 256, 0, stream>>>(
            x + (size_t)b0 * HW * HW, xb, n4);
        // T' = M * x^T   (A = M [960x768], Bt = xb [768 rows x 768 K])
        gemm_bt<<<dim3(6, 8, cur), 256, 0, stream>>>(
            Mb, HW, xb, (long long)HW * HW, HW,
            T, (long long)OHW * HW, HW, OHW, HW, HW, 0);
        // out = M * T'^T (A = M, Bt = T' [960 rows x 768 K])
        gemm_bt<<<dim3(8, 8, cur), 256, 0, stream>>>(
            Mb, HW, T, (long long)OHW * HW, HW,
            out + (size_t)b0 * OHW * OHW, (long long)OHW * OHW, OHW,
            OHW, OHW, HW, 1);
    }
    (void)in_sizes; (void)n_in; (void)out_size;
}

// Round 2
// 413.633 us; speedup vs baseline: 1.0291x; 1.0151x over previous
//
#include <hip/hip_runtime.h>

// DCT upsample: out[img] = M * x[img] * M^T,  M = E*D (960x768), closed-form
// Dirichlet kernel:
//   M[i][n] = (1 + S(p1) + S(p2))/960,  S = sin(767u)cos(768u)/sin(u), u=pi*p/15360
// Restructured so M is the A operand of BOTH gemms:
//   T' = M * x^T      (Bt = x row-major, bf16-converted)   [960 x 768]
//   out = M * T'^T    (Bt = T')                            [960 x 960]
// V3: 256x256 8-phase schedule (T2+T3+T4+T5 per guide §5.5):
//   512 threads = 8 waves (2M x 4N), wave tile 128x64 (8x4 mfma_16x16x32),
//   BK=64, LDS = 2 x (256x64 A + 256x64 B) bf16 = 128 KiB double buffer.
//   4 phases per K-tile = C-quadrants (mig,nig): reads 12/4/8/0 ds_read_b128,
//   each phase: [reads | glds-stage] bar; lgkmcnt(0)+sched_barrier; prio1;
//   16 MFMA; prio0; bar.  All staging for tile t+1 issued in P1(A)/P2(B) of
//   tile t, single vmcnt(0) at P4 (>=2 phases of cover -> empty drain).
//   XOR chunk swizzle: phys 16B-chunk p of row r holds logical p^((r>>1)&7),
//   applied on the per-lane global source (glds dest stays linear); fragment
//   reads apply the same XOR -> conflict-free ds_read_b128 (verified 0 conf).

#define HW 768
#define OHW 960
#define NIMG 48

typedef __attribute__((ext_vector_type(8))) short short8;
typedef __attribute__((ext_vector_type(4))) float f32x4;
typedef __attribute__((ext_vector_type(4))) float float4v;
typedef __attribute__((ext_vector_type(4))) unsigned short us4;

__device__ __forceinline__ unsigned short f2bf(float f) {
    union { float f; unsigned int u; } v; v.f = f;
    unsigned int u = v.u;
    return (unsigned short)((u + 0x7FFFu + ((u >> 16) & 1u)) >> 16);
}

__device__ __forceinline__ void glds16(const void* g, void* l) {
    __builtin_amdgcn_global_load_lds(
        (const __attribute__((address_space(1))) void*)g,
        (__attribute__((address_space(3))) void*)l, 16, 0, 0);
}

// ---------------- closed-form M fill ----------------
__device__ __forceinline__ float dsum(int p) {
    int n1 = (767 * p) % 30720;
    int n2 = (768 * p) % 30720;
    const float w = (float)(3.14159265358979323846 / 15360.0);
    return sinf((float)n1 * w) * cosf((float)n2 * w) / sinf((float)p * w);
}

__global__ void fill_M(unsigned short* __restrict__ Mb) {
    int idx = blockIdx.x * 256 + threadIdx.x;
    if (idx >= OHW * HW) return;
    int i = idx / HW, n = idx - i * HW;
    int a = 8 * i + 4, b = 10 * n + 5;
    int p1 = a + b;
    int p2 = a - b; if (p2 < 0) p2 += 15360;
    float m = (1.0f + dsum(p1) + dsum(p2)) * (1.0f / 960.0f);
    Mb[idx] = f2bf(m);
}

// ---------------- streaming f32 -> bf16 convert ----------------
__global__ void conv_bf16(const float* __restrict__ x, unsigned short* __restrict__ xb, int n4) {
    int i = blockIdx.x * 256 + threadIdx.x;
    if (i >= n4) return;
    float4v v = *(const float4v*)(x + (size_t)i * 4);
    us4 o; o.x = f2bf(v.x); o.y = f2bf(v.y); o.z = f2bf(v.z); o.w = f2bf(v.w);
    *(us4*)(xb + (size_t)i * 4) = o;
}

// ---------------- MFMA GEMM (B-transposed, K-major operands) ----------------
#define ASM_BAR   asm volatile("s_barrier" ::: "memory")
#define ASM_VM0   asm volatile("s_waitcnt vmcnt(0)" ::: "memory")
#define ASM_LGKM8 asm volatile("s_waitcnt lgkmcnt(8)" ::: "memory")
#define ASM_LGKM0 do { asm volatile("s_waitcnt lgkmcnt(0)" ::: "memory"); \
                       __builtin_amdgcn_sched_barrier(0); } while (0)

__global__ __launch_bounds__(512, 2) void gemm_bt(
    const unsigned short* __restrict__ A, int lda,
    const unsigned short* __restrict__ Bg, long long strideB, int ldb,
    void* __restrict__ Cg, long long strideC, int ldc,
    int Md, int Nd, int Kd, int out_f32)
{
    __shared__ unsigned short As[2][256 * 64];
    __shared__ unsigned short Bs[2][256 * 64];

    const int tid = threadIdx.x;
    const int wave = tid >> 6, lane = tid & 63;
    const int wm = wave >> 2, wn = wave & 3;     // 2 x 4 wave grid
    const int t16 = lane & 15, quad = lane >> 4;
    const int z = blockIdx.z;

    const unsigned short* Bp = Bg + (size_t)z * strideB;
    const int mb = blockIdx.y * 256, nbb = blockIdx.x * 256;

    f32x4 acc[8][4];
#pragma unroll
    for (int i = 0; i < 8; ++i)
#pragma unroll
        for (int j = 0; j < 4; ++j)
            acc[i][j] = (f32x4){0.f, 0.f, 0.f, 0.f};

    // ---- staging geometry (pre-swizzled per-lane global source) ----
    // chunk c = tid + 512*j  ->  row r = c>>3 (0..255), phys p = c&7 = tid&7
    // logical chunk l = p ^ ((r>>1)&7) = (tid&7) ^ ((tid>>4)&7)  (j-indep)
    const int srow = tid >> 3;                             // 0..63
    const int klog = ((tid & 7) ^ ((tid >> 4) & 7)) * 8;   // shorts
    const unsigned short* pA[4];
    const unsigned short* pB[4];
#pragma unroll
    for (int j = 0; j < 4; ++j) {
        int ra = mb + srow + 64 * j;  if (ra >= Md) ra = Md - 1;
        int rb = nbb + srow + 64 * j; if (rb >= Nd) rb = Nd - 1;
        pA[j] = A  + (size_t)ra * lda + klog;
        pB[j] = Bp + (size_t)rb * ldb + klog;
    }
    const int dOff = tid * 8;   // LDS shorts; + j*4096 per glds

    // ---- fragment read offsets (shorts) ----
    // row = base16*16 + t16 with base16*16 % 16 == 0  ->  (row>>1)&7 = (t16>>1)&7
    const int swz = (t16 >> 1) & 7;
    const int ph0 = ((0 * 4 + quad) ^ swz) * 8;
    const int ph1 = ((1 * 4 + quad) ^ swz) * 8;
    const int aRow = (wm * 128 + t16) * 64;
    const int bRow = (wn * 64 + t16) * 64;

#define RD_A(mig) do { _Pragma("unroll")                                      \
    for (int mi_ = 0; mi_ < 4; ++mi_) {                                       \
        afr[mi_][0] = *(const short8*)(Asc + aRow + ((mig)*4+mi_)*1024 + ph0);\
        afr[mi_][1] = *(const short8*)(Asc + aRow + ((mig)*4+mi_)*1024 + ph1);\
    } } while (0)

#define RD_B(dst, nig) do { _Pragma("unroll")                                 \
    for (int ni_ = 0; ni_ < 2; ++ni_) {                                       \
        dst[ni_][0] = *(const short8*)(Bsc + bRow + ((nig)*2+ni_)*1024 + ph0);\
        dst[ni_][1] = *(const short8*)(Bsc + bRow + ((nig)*2+ni_)*1024 + ph1);\
    } } while (0)

#define MMA_Q(mig, nig, bfv) do {                                             \
    __builtin_amdgcn_s_setprio(1);                                            \
    _Pragma("unroll")                                                         \
    for (int ks_ = 0; ks_ < 2; ++ks_)                                         \
    _Pragma("unroll")                                                         \
    for (int mi_ = 0; mi_ < 4; ++mi_)                                         \
    _Pragma("unroll")                                                         \
    for (int ni_ = 0; ni_ < 2; ++ni_)                                         \
        acc[(mig)*4+mi_][(nig)*2+ni_] =                                       \
            __builtin_amdgcn_mfma_f32_16x16x32_bf16(                          \
                afr[mi_][ks_], bfv[ni_][ks_],                                 \
                acc[(mig)*4+mi_][(nig)*2+ni_], 0, 0, 0);                      \
    __builtin_amdgcn_s_setprio(0); } while (0)

#define STG_A(buf, kt) do { _Pragma("unroll")                                 \
    for (int j_ = 0; j_ < 4; ++j_)                                            \
        glds16(pA[j_] + (kt) * 64, &As[buf][0] + dOff + j_ * 4096); } while (0)
#define STG_B(buf, kt) do { _Pragma("unroll")                                 \
    for (int j_ = 0; j_ < 4; ++j_)                                            \
        glds16(pB[j_] + (kt) * 64, &Bs[buf][0] + dOff + j_ * 4096); } while (0)

    const int NT = Kd >> 6;   // K=768 -> 12 tiles

    // prologue: stage tile 0 into buf 0
    STG_A(0, 0); STG_B(0, 0);
    ASM_VM0;
    ASM_BAR;

    for (int t = 0; t < NT; ++t) {
        const int cur = t & 1, nxt = cur ^ 1;
        const unsigned short* Asc = &As[cur][0];
        const unsigned short* Bsc = &Bs[cur][0];
        const bool pf = (t + 1 < NT);
        short8 afr[4][2], bf0[2][2], bf1[2][2];

        // ---- P1: Q00  (12 reads; stage A of t+1) ----
        RD_A(0); RD_B(bf0, 0);
        if (pf) STG_A(nxt, t + 1);
        ASM_LGKM8;
        ASM_BAR;
        ASM_LGKM0;
        MMA_Q(0, 0, bf0);
        ASM_BAR;

        // ---- P2: Q01  (4 reads; stage B of t+1) ----
        RD_B(bf1, 1);
        if (pf) STG_B(nxt, t + 1);
        ASM_BAR;
        ASM_LGKM0;
        MMA_Q(0, 1, bf1);
        ASM_BAR;

        // ---- P3: Q10  (8 reads) ----
        RD_A(1);
        ASM_BAR;
        ASM_LGKM0;
        MMA_Q(1, 0, bf0);
        ASM_BAR;

        // ---- P4: Q11  (0 reads; tile-boundary wait) ----
        MMA_Q(1, 1, bf1);
        ASM_VM0;     // staging for t+1 issued >=2 phases ago -> cheap drain
        ASM_BAR;
    }

#undef RD_A
#undef RD_B
#undef MMA_Q
#undef STG_A
#undef STG_B

    // epilogue: D row = quad*4 + r, col = t16 within each 16x16 tile
    const int gr0 = mb + wm * 128;
    const int gc0 = nbb + wn * 64;
    if (out_f32) {
        float* C = (float*)Cg + (size_t)z * strideC;
#pragma unroll
        for (int mi = 0; mi < 8; ++mi)
#pragma unroll
            for (int ni = 0; ni < 4; ++ni) {
                int col = gc0 + ni * 16 + t16;
                if (col < Nd) {
#pragma unroll
                    for (int r = 0; r < 4; ++r) {
                        int rowg = gr0 + mi * 16 + quad * 4 + r;
                        if (rowg < Md) C[(size_t)rowg * ldc + col] = acc[mi][ni][r];
                    }
                }
            }
    } else {
        unsigned short* C = (unsigned short*)Cg + (size_t)z * strideC;
#pragma unroll
        for (int mi = 0; mi < 8; ++mi)
#pragma unroll
            for (int ni = 0; ni < 4; ++ni) {
                int col = gc0 + ni * 16 + t16;
                if (col < Nd) {
#pragma unroll
                    for (int r = 0; r < 4; ++r) {
                        int rowg = gr0 + mi * 16 + quad * 4 + r;
                        if (rowg < Md) C[(size_t)rowg * ldc + col] = f2bf(acc[mi][ni][r]);
                    }
                }
            }
    }
}

extern "C" void kernel_launch(void* const* d_in, const int* in_sizes, int n_in,
                              void* d_out, int out_size, void* d_ws, size_t ws_size,
                              hipStream_t stream) {
    const float* x = (const float*)d_in[0];
    float* out = (float*)d_out;
    char* ws = (char*)d_ws;

    size_t offM  = 0;
    size_t fixed = offM + (size_t)OHW * HW * 2;              // 1,474,560 B
    size_t perImg = (size_t)HW * HW * 2 + (size_t)OHW * HW * 2;

    int nb = 1;
    if (ws_size > fixed + perImg) {
        size_t q = (ws_size - fixed) / perImg;
        nb = (q > 48) ? 48 : (int)q;
        if (nb < 1) nb = 1;
    }

    unsigned short* Mb = (unsigned short*)(ws + offM);
    unsigned short* xb = (unsigned short*)(ws + fixed);
    unsigned short* T  = (unsigned short*)(ws + fixed + (size_t)nb * HW * HW * 2);

    fill_M<<<(OHW * HW + 255) / 256, 256, 0, stream>>>(Mb);

    for (int b0 = 0; b0 < NIMG; b0 += nb) {
        int cur = NIMG - b0; if (cur > nb) cur = nb;
        // xb = bf16(x[b0..b0+cur]), straight streaming convert (no transpose)
        int n4 = cur * (HW * HW / 4);
        conv_bf16<<<(n4 + 255) / 256, 256, 0, stream>>>(
            x + (size_t)b0 * HW * HW, xb, n4);
        // T' = M * x^T   (A = M [960x768], Bt = xb [768 rows x 768 K])
        gemm_bt<<<dim3(3, 4, cur), 512, 0, stream>>>(
            Mb, HW, xb, (long long)HW * HW, HW,
            T, (long long)OHW * HW, HW, OHW, HW, HW, 0);
        // out = M * T'^T (A = M, Bt = T' [960 rows x 768 K])
        gemm_bt<<<dim3(4, 4, cur), 512, 0, stream>>>(
            Mb, HW, T, (long long)OHW * HW, HW,
            out + (size_t)b0 * OHW * OHW, (long long)OHW * OHW, OHW,
            OHW, OHW, HW, 1);
    }
    (void)in_sizes; (void)n_in; (void)out_size;
}